// Round 8
// baseline (113.164 us; speedup 1.0000x reference)
//
#include <hip/hip_runtime.h>
#include <hip/hip_bf16.h>

// attention_84464826843938: additive-attention pooling, MI355X (gfx950)
//
// R8: batched GEMM -> ONE GEMM [B*R=16384, F=2048] @ [F, DIM=512] (W shared
// across b). Tile 128x256, BK=64, 512thr/8 waves, wave=64x64 (32 MFMA/step).
// R7-proven pieces kept: fp32 DMA ring + per-wave-self-consistent shared cvt
// (each wave cvts exactly the rows it DMA'd), frg dbuf, B-frags in regs,
// counted vmcnt (keep newest 8 = B(kt+1)), 1 barrier/step, setprio on MFMA.
// Grid 256 = 1 block/CU; XCD-bijective chunking: logical=(bid%8)*32+bid/8
// -> each XCD gets 16 rowblks x 2 colblks (A panel fetched once per XCD).

#define B_ 256
#define R_ 64
#define F_ 2048
#define H_ 512
#define DIM_ 512

typedef short bf16x8 __attribute__((ext_vector_type(8)));
typedef float f32x4 __attribute__((ext_vector_type(4)));

__device__ __forceinline__ ushort f2bf(float x) {
  __hip_bfloat16 h = __float2bfloat16(x);
  return __builtin_bit_cast(ushort, h);
}

__device__ __forceinline__ uint4 pack8(float4 x, float4 y) {
  uint4 r;
  r.x = (uint)f2bf(x.x) | ((uint)f2bf(x.y) << 16);
  r.y = (uint)f2bf(x.z) | ((uint)f2bf(x.w) << 16);
  r.z = (uint)f2bf(y.x) | ((uint)f2bf(y.y) << 16);
  r.w = (uint)f2bf(y.z) | ((uint)f2bf(y.w) << 16);
  return r;
}

__device__ __forceinline__ void gld16(const float* g, float* l) {
  __builtin_amdgcn_global_load_lds(
      (const __attribute__((address_space(1))) unsigned int*)(g),
      (__attribute__((address_space(3))) unsigned int*)(l),
      16, 0, 0);
}

// wpack[((kt32*32 + ctg)*64 + g*16 + c)*8 + i] = bf16(W_w[kt32*32 + g*8 + i][ctg*16 + c])
__global__ void pack_w_k(const float* __restrict__ Ww, ushort* __restrict__ wpack) {
  int idx = blockIdx.x * 256 + threadIdx.x;
  float v = Ww[idx];
  int k = idx >> 9;
  int d = idx & 511;
  int kt = k >> 5, kr = k & 31;
  int g = kr >> 3, i = kr & 7;
  int ctg = d >> 4, c = d & 15;
  size_t dst = ((size_t)((kt * 32 + ctg) * 64 + g * 16 + c)) * 8 + (size_t)i;
  wpack[dst] = f2bf(v);
}

// p'[b][d] = prev[b]@W2_w[:,d] + W2_b[d] + W_b[d]
__global__ __launch_bounds__(256) void prep_p_k(const float* __restrict__ prev,
                                                const float* __restrict__ W2w,
                                                const float* __restrict__ W2b,
                                                const float* __restrict__ Wb,
                                                float* __restrict__ pprime) {
  __shared__ float lprev[8][H_];
  int bg = blockIdx.x >> 3;
  int d0 = (blockIdx.x & 7) * 64;
  int t = threadIdx.x;
  const float4* src = reinterpret_cast<const float4*>(prev + (size_t)bg * 8 * H_);
  float4* dst = reinterpret_cast<float4*>(&lprev[0][0]);
  for (int i = t; i < 8 * H_ / 4; i += 256) dst[i] = src[i];
  __syncthreads();
  int d = d0 + (t & 63);
  int bq = t >> 6;
  float a0 = 0.f, a1 = 0.f;
  #pragma unroll 8
  for (int h = 0; h < H_; ++h) {
    float wv = W2w[h * DIM_ + d];
    a0 += lprev[bq][h] * wv;
    a1 += lprev[bq + 4][h] * wv;
  }
  float bias = W2b[d] + Wb[d];
  pprime[(size_t)(bg * 8 + bq) * DIM_ + d] = a0 + bias;
  pprime[(size_t)(bg * 8 + bq + 4) * DIM_ + d] = a1 + bias;
}

__device__ __forceinline__ float fast_tanh(float x) {
  float e = __expf(2.f * x);
  return 1.f - 2.f / (e + 1.f);
}

// sp[b*2+colblk][r] = sum_{d in colblk's 256 cols} tanh(c+p')*W3
__global__ __launch_bounds__(512, 2) void score_k(const float* __restrict__ feat,
                                                  const ushort* __restrict__ wpack,
                                                  const float* __restrict__ pprime,
                                                  const float* __restrict__ W3,
                                                  float* __restrict__ sp) {
  int bid = blockIdx.x;
  int logical = (bid & 7) * 32 + (bid >> 3);   // XCD-bijective chunk (256%8==0)
  int rowblk = logical >> 1;                   // 0..127: rows rowblk*128 (2 b's)
  int colblk = logical & 1;                    // 0..1:   cols colblk*256
  int t = threadIdx.x;
  int wid = t >> 6;                            // 8 waves: 2M x 4N
  int wm = wid >> 2, wn = wid & 3;             // wave owns 64 rows x 64 cols
  int l = t & 63, l15 = l & 15, g = l >> 4;

  const float* featT = feat + (size_t)rowblk * 128 * F_;

  __shared__ float4 raw4[2][2048];    // 2 x 32KB: raw[buf][row*16 + chunk] fp32
                                      // content: global chunk (chunk ^ (row&15))
  __shared__ uint4 frg[2][1024];      // 2 x 16KB: frg[buf][kc*128 + row] bf16x8
  __shared__ float lds_part[8][R_];

  f32x4 acc[4][4];
  #pragma unroll
  for (int rt = 0; rt < 4; ++rt)
    #pragma unroll
    for (int ct = 0; ct < 4; ++ct)
      acc[rt][ct] = (f32x4){0.f, 0.f, 0.f, 0.f};

  // ---- DMA geometry: wave wid stages rows [wid*16, wid*16+16), 4 gld16 (j),
  // each covering rows wid*16+j*4+(l>>4), chunk l15, source chunk l15^(row&15).
  const float* sgj[4];
  #pragma unroll
  for (int j = 0; j < 4; ++j) {
    int r_ = wid * 16 + j * 4 + g;
    int ch = l15 ^ (r_ & 15);
    sgj[j] = featT + (size_t)r_ * F_ + ch * 4;
  }

  // ---- cvt geometry: thread t -> row t>>2 (in its own wave's DMA rows),
  // frag chunks kc = (t&3)*2 + {0,1}
  int crow = t >> 2;
  int rm = crow & 15;
  int cq = (t & 3) * 2;

  // ---- B geometry
  int ctg0 = colblk * 16 + wn * 4;

#define STAGE(buf, kt) do {                                          \
    _Pragma("unroll")                                                \
    for (int j_ = 0; j_ < 4; ++j_)                                   \
      gld16(sgj[j_] + (size_t)(kt) * 64,                             \
            (float*)&raw4[buf][(wid * 16 + j_ * 4) * 16]);           \
  } while (0)

#define LOADB(dst, kt) do {                                          \
    _Pragma("unroll")                                                \
    for (int s_ = 0; s_ < 2; ++s_)                                   \
      _Pragma("unroll")                                              \
      for (int ct_ = 0; ct_ < 4; ++ct_)                              \
        dst[s_][ct_] = *reinterpret_cast<const uint4*>(              \
            wpack + ((size_t)((kt) * 2 + s_) * 32 + (ctg0 + ct_)) * 512 + (size_t)l * 8); \
  } while (0)

#define CVT(rb, fb) do {                                             \
    _Pragma("unroll")                                                \
    for (int h_ = 0; h_ < 2; ++h_) {                                 \
      int kc_ = cq + h_;                                             \
      float4 x_ = raw4[rb][crow * 16 + ((kc_ * 2) ^ rm)];            \
      float4 y_ = raw4[rb][crow * 16 + ((kc_ * 2 + 1) ^ rm)];        \
      frg[fb][kc_ * 128 + crow] = pack8(x_, y_);                     \
    }                                                                \
  } while (0)

#define MFMA_STEP(fb) do {                                           \
    _Pragma("unroll")                                                \
    for (int s_ = 0; s_ < 2; ++s_) {                                 \
      bf16x8 af_[4];                                                 \
      _Pragma("unroll")                                              \
      for (int rt_ = 0; rt_ < 4; ++rt_)                              \
        af_[rt_] = __builtin_bit_cast(bf16x8,                        \
            frg[fb][(s_ * 4 + g) * 128 + wm * 64 + rt_ * 16 + l15]); \
      _Pragma("unroll")                                              \
      for (int ct_ = 0; ct_ < 4; ++ct_) {                            \
        bf16x8 bv_ = __builtin_bit_cast(bf16x8, bc[s_][ct_]);        \
        _Pragma("unroll")                                            \
        for (int rt_ = 0; rt_ < 4; ++rt_)                            \
          acc[rt_][ct_] = __builtin_amdgcn_mfma_f32_16x16x32_bf16(   \
              af_[rt_], bv_, acc[rt_][ct_], 0, 0, 0);                \
      }                                                              \
    }                                                                \
  } while (0)

  uint4 bc[2][4], bn[2][4];
  // prologue: D0 -> raw0, D1 -> raw1, B0 -> regs. Per-wave outstanding = 16;
  // need own D0 for CVT (wave cvts exactly its own DMA rows) -> keep 12.
  STAGE(0, 0);
  STAGE(1, 1);
  LOADB(bc, 0);
  asm volatile("s_waitcnt vmcnt(12)" ::: "memory");
  CVT(0, 0);                          // no barrier needed: per-wave rows

  for (int kt = 0; kt < 32; ++kt) {
    if (kt < 31) LOADB(bn, kt + 1);
    // steady per-wave outstanding: D(kt+1)=4, B(kt)=8, B(kt+1)=8 -> keep 8
    // (drains D(kt+1) for CVT and B(kt) for MFMA). lgkmcnt(0): CVT writes +
    // last step's frag reads done before barrier.
    if (kt < 31) {
      asm volatile("s_waitcnt vmcnt(8) lgkmcnt(0)" ::: "memory");
    } else {
      asm volatile("s_waitcnt vmcnt(0) lgkmcnt(0)" ::: "memory");
    }
    __builtin_amdgcn_s_barrier();
    asm volatile("" ::: "memory");

    if (kt < 30) STAGE(kt & 1, kt + 2);     // raw[kt&1]: CVT(kt) reads drained
    if (kt < 31) CVT((kt + 1) & 1, (kt + 1) & 1);
    __builtin_amdgcn_s_setprio(1);
    MFMA_STEP(kt & 1);
    __builtin_amdgcn_s_setprio(0);
    if (kt < 31) {
      #pragma unroll
      for (int s_ = 0; s_ < 2; ++s_)
        #pragma unroll
        for (int ct_ = 0; ct_ < 4; ++ct_)
          bc[s_][ct_] = bn[s_][ct_];
    }
  }

#undef STAGE
#undef LOADB
#undef CVT
#undef MFMA_STEP

  // ---- epilogue: tanh + W3 dot in registers.
  // acc[rt][ct][j] = c[row = wm*64 + rt*16 + g*4 + j][col = colblk*256 + wn*64 + ct*16 + l15]
  // rows [0,64) -> b0 = rowblk*2 + 0; rows [64,128) -> b0 + 1 (selected by wm).
  int b0 = rowblk * 2;
  float pp[4], w3v[4];
  #pragma unroll
  for (int ct = 0; ct < 4; ++ct) {
    int col = colblk * 256 + wn * 64 + ct * 16 + l15;
    pp[ct] = pprime[(b0 + wm) * DIM_ + col];
    w3v[ct] = W3[col];
  }
  #pragma unroll
  for (int rt = 0; rt < 4; ++rt) {
    #pragma unroll
    for (int j = 0; j < 4; ++j) {
      float v = fast_tanh(acc[rt][0][j] + pp[0]) * w3v[0]
              + fast_tanh(acc[rt][1][j] + pp[1]) * w3v[1]
              + fast_tanh(acc[rt][2][j] + pp[2]) * w3v[2]
              + fast_tanh(acc[rt][3][j] + pp[3]) * w3v[3];
      v += __shfl_xor(v, 1);
      v += __shfl_xor(v, 2);
      v += __shfl_xor(v, 4);
      v += __shfl_xor(v, 8);
      if (l15 == 0) lds_part[wid][rt * 16 + g * 4 + j] = v;
    }
  }
  __syncthreads();

  if (t < 128) {
    int bb = t >> 6;                  // which of the 2 b's
    int r = t & 63;
    float s = lds_part[bb * 4 + 0][r] + lds_part[bb * 4 + 1][r]
            + lds_part[bb * 4 + 2][r] + lds_part[bb * 4 + 3][r];
    sp[((size_t)(b0 + bb) * 2 + colblk) * R_ + r] = s;
  }
}

// softmax + weighted sum: grid = B*4, 256 thr, 512 f per block
__global__ __launch_bounds__(256) void wsum_k(const float* __restrict__ feat,
                                              const float* __restrict__ sp,
                                              float* __restrict__ out) {
  int b = blockIdx.x >> 2;
  int f0 = (blockIdx.x & 3) * 512;
  int t = threadIdx.x;
  __shared__ float lds_aw[R_];

  if (t < R_) {
    float s = sp[((size_t)b * 2 + 0) * R_ + t] + sp[((size_t)b * 2 + 1) * R_ + t];
    float m = s;
    #pragma unroll
    for (int off = 32; off >= 1; off >>= 1) m = fmaxf(m, __shfl_xor(m, off));
    float e = __expf(s - m);
    float su = e;
    #pragma unroll
    for (int off = 32; off >= 1; off >>= 1) su += __shfl_xor(su, off);
    lds_aw[t] = e / su;
  }
  __syncthreads();

  const float* fp = feat + (size_t)b * R_ * F_ + f0 + t * 2;
  float qx = 0.f, qy = 0.f;
  #pragma unroll 8
  for (int r = 0; r < R_; ++r) {
    float a = lds_aw[r];
    float2 v = *reinterpret_cast<const float2*>(fp + (size_t)r * F_);
    qx += a * v.x;
    qy += a * v.y;
  }
  *reinterpret_cast<float2*>(out + (size_t)b * F_ + f0 + t * 2) = (float2){qx, qy};
}

extern "C" void kernel_launch(void* const* d_in, const int* in_sizes, int n_in,
                              void* d_out, int out_size, void* d_ws, size_t ws_size,
                              hipStream_t stream) {
  const float* feat = (const float*)d_in[0];   // [B,R,F] == [16384, 2048]
  const float* prev = (const float*)d_in[1];   // [B,H]
  const float* Ww   = (const float*)d_in[2];   // [F,DIM]
  const float* Wb   = (const float*)d_in[3];   // [DIM]
  const float* W2w  = (const float*)d_in[4];   // [H,DIM]
  const float* W2b  = (const float*)d_in[5];   // [DIM]
  const float* W3w  = (const float*)d_in[6];   // [DIM,1]
  // d_in[7] = W3_b: cancels in softmax
  float* out = (float*)d_out;

  ushort* wpack  = (ushort*)d_ws;                                          // 2 MB
  float*  pprime = (float*)((char*)d_ws + (size_t)F_ * DIM_ * 2);          // 512 KB
  float*  sp     = (float*)((char*)d_ws + (size_t)F_ * DIM_ * 2
                                        + (size_t)B_ * DIM_ * 4);          // 128 KB

  pack_w_k<<<(F_ * DIM_) / 256, 256, 0, stream>>>(Ww, wpack);
  prep_p_k<<<256, 256, 0, stream>>>(prev, W2w, W2b, Wb, pprime);
  score_k<<<256, 512, 0, stream>>>(feat, wpack, pprime, W3w, sp);
  wsum_k<<<B_ * 4, 256, 0, stream>>>(feat, sp, out);
}

// Round 9
// 103.558 us; speedup vs baseline: 1.0928x; 1.0928x over previous
//
#include <hip/hip_runtime.h>
#include <hip/hip_bf16.h>

// attention_84464826843938: additive-attention pooling, MI355X (gfx950)
//
// R9: FUSED kernel — score GEMM (BM=64 rows = one b, BN=512 = full DIM) +
// softmax + weighted feature sum in ONE block per b. Deletes wsum_k's 134 MB
// HBM re-read (feat[b] 512KB is L2-hot from the block's own GEMM stream) and
// the sp round-trip. Keeps R7/R8-proven pieces: gld16 raw fp32 ring (3-deep,
// src-XOR-swizzle), per-wave-self-consistent cvt (no barrier for raw), shared
// bf16 frg dbuf (XOR both sides), counted vmcnt(8) keeping B(kt+1) in flight,
// 1 barrier/step, setprio on MFMA. Grid 256 = 1 block/CU; A block-private so
// no XCD swizzle needed; wpack (2MB) L2-resident per XCD.

#define B_ 256
#define R_ 64
#define F_ 2048
#define H_ 512
#define DIM_ 512

typedef short bf16x8 __attribute__((ext_vector_type(8)));
typedef float f32x4 __attribute__((ext_vector_type(4)));

__device__ __forceinline__ ushort f2bf(float x) {
  __hip_bfloat16 h = __float2bfloat16(x);
  return __builtin_bit_cast(ushort, h);
}

__device__ __forceinline__ uint4 pack8(float4 x, float4 y) {
  uint4 r;
  r.x = (uint)f2bf(x.x) | ((uint)f2bf(x.y) << 16);
  r.y = (uint)f2bf(x.z) | ((uint)f2bf(x.w) << 16);
  r.z = (uint)f2bf(y.x) | ((uint)f2bf(y.y) << 16);
  r.w = (uint)f2bf(y.z) | ((uint)f2bf(y.w) << 16);
  return r;
}

__device__ __forceinline__ void gld16(const float* g, float* l) {
  __builtin_amdgcn_global_load_lds(
      (const __attribute__((address_space(1))) unsigned int*)(g),
      (__attribute__((address_space(3))) unsigned int*)(l),
      16, 0, 0);
}

// wpack[((kt32*32 + ctg)*64 + g*16 + c)*8 + i] = bf16(W_w[kt32*32 + g*8 + i][ctg*16 + c])
__global__ void pack_w_k(const float* __restrict__ Ww, ushort* __restrict__ wpack) {
  int idx = blockIdx.x * 256 + threadIdx.x;
  float v = Ww[idx];
  int k = idx >> 9;
  int d = idx & 511;
  int kt = k >> 5, kr = k & 31;
  int g = kr >> 3, i = kr & 7;
  int ctg = d >> 4, c = d & 15;
  size_t dst = ((size_t)((kt * 32 + ctg) * 64 + g * 16 + c)) * 8 + (size_t)i;
  wpack[dst] = f2bf(v);
}

// p'[b][d] = prev[b]@W2_w[:,d] + W2_b[d] + W_b[d]
__global__ __launch_bounds__(256) void prep_p_k(const float* __restrict__ prev,
                                                const float* __restrict__ W2w,
                                                const float* __restrict__ W2b,
                                                const float* __restrict__ Wb,
                                                float* __restrict__ pprime) {
  __shared__ float lprev[8][H_];
  int bg = blockIdx.x >> 3;
  int d0 = (blockIdx.x & 7) * 64;
  int t = threadIdx.x;
  const float4* src = reinterpret_cast<const float4*>(prev + (size_t)bg * 8 * H_);
  float4* dst = reinterpret_cast<float4*>(&lprev[0][0]);
  for (int i = t; i < 8 * H_ / 4; i += 256) dst[i] = src[i];
  __syncthreads();
  int d = d0 + (t & 63);
  int bq = t >> 6;
  float a0 = 0.f, a1 = 0.f;
  #pragma unroll 8
  for (int h = 0; h < H_; ++h) {
    float wv = W2w[h * DIM_ + d];
    a0 += lprev[bq][h] * wv;
    a1 += lprev[bq + 4][h] * wv;
  }
  float bias = W2b[d] + Wb[d];
  pprime[(size_t)(bg * 8 + bq) * DIM_ + d] = a0 + bias;
  pprime[(size_t)(bg * 8 + bq + 4) * DIM_ + d] = a1 + bias;
}

__device__ __forceinline__ float fast_tanh(float x) {
  float e = __expf(2.f * x);
  return 1.f - 2.f / (e + 1.f);
}

// One block per b: c = tanh(feat[b]@W + p'), score = c@W3, softmax, q = aw^T feat[b]
__global__ __launch_bounds__(512, 2) void fused_k(const float* __restrict__ feat,
                                                  const ushort* __restrict__ wpack,
                                                  const float* __restrict__ pprime,
                                                  const float* __restrict__ W3,
                                                  float* __restrict__ out) {
  int b = blockIdx.x;
  int t = threadIdx.x;
  int wid = t >> 6;                     // 8 waves; wave owns cols [wid*64,+64)
  int l = t & 63;
  int l15 = l & 15, g = l >> 4;
  const float* featB = feat + (size_t)b * R_ * F_;

  // raw ring: raw4[rb][row*16 + c]: holds global chunk (c ^ (row&15)), fp32
  __shared__ float4 raw4[3][1024];      // 3 x 16 KB
  // frg[fb][kc*64 + (row ^ kc)] = bf16 A[row][kc*8..+8]
  __shared__ uint4 frg[2][512];         // 2 x 8 KB
  __shared__ float lds_part[8][R_];
  __shared__ float lds_aw[R_];

  f32x4 acc[4][4];
  #pragma unroll
  for (int rt = 0; rt < 4; ++rt)
    #pragma unroll
    for (int ct = 0; ct < 4; ++ct)
      acc[rt][ct] = (f32x4){0.f, 0.f, 0.f, 0.f};

  // DMA: wave wid stages rows [wid*8, wid*8+8): 2 gld16 (j=0,1), rows +j*4+(l>>4)
  const float* sgj[2];
  #pragma unroll
  for (int j = 0; j < 2; ++j) {
    int r_ = wid * 8 + j * 4 + g;
    sgj[j] = featB + (size_t)r_ * F_ + (size_t)((l15 ^ (r_ & 15)) * 4);
  }

  // cvt: lane covers row crow = wid*8 + (l>>3), k-chunk kc = l&7 (8 elems)
  int crow = wid * 8 + (l >> 3);
  int rm = crow & 15;
  int kcw = l & 7;
  int c2 = kcw * 2;

#define STAGE(buf, kt) do {                                            \
    gld16(sgj[0] + (size_t)(kt) * 64, (float*)&raw4[buf][(wid * 8) * 16]);      \
    gld16(sgj[1] + (size_t)(kt) * 64, (float*)&raw4[buf][(wid * 8 + 4) * 16]);  \
  } while (0)

#define LOADB(dst, kt) do {                                            \
    _Pragma("unroll")                                                  \
    for (int s_ = 0; s_ < 2; ++s_)                                     \
      _Pragma("unroll")                                                \
      for (int ct_ = 0; ct_ < 4; ++ct_)                                \
        dst[s_][ct_] = *reinterpret_cast<const uint4*>(                \
            wpack + ((size_t)((kt) * 2 + s_) * 32 + (wid * 4 + ct_)) * 512 + (size_t)l * 8); \
  } while (0)

#define CVT(rb, fb) do {                                               \
    float4 x_ = raw4[rb][crow * 16 + (c2 ^ rm)];                       \
    float4 y_ = raw4[rb][crow * 16 + ((c2 + 1) ^ rm)];                 \
    frg[fb][kcw * 64 + (crow ^ kcw)] = pack8(x_, y_);                  \
  } while (0)

#define MFMA_STEP(fb) do {                                             \
    _Pragma("unroll")                                                  \
    for (int s_ = 0; s_ < 2; ++s_) {                                   \
      bf16x8 af_[4];                                                   \
      int kc_ = s_ * 4 + g;                                            \
      _Pragma("unroll")                                                \
      for (int rt_ = 0; rt_ < 4; ++rt_)                                \
        af_[rt_] = __builtin_bit_cast(bf16x8,                          \
            frg[fb][kc_ * 64 + ((rt_ * 16 + l15) ^ kc_)]);             \
      _Pragma("unroll")                                                \
      for (int ct_ = 0; ct_ < 4; ++ct_) {                              \
        bf16x8 bv_ = __builtin_bit_cast(bf16x8, bc[s_][ct_]);          \
        _Pragma("unroll")                                              \
        for (int rt_ = 0; rt_ < 4; ++rt_)                              \
          acc[rt_][ct_] = __builtin_amdgcn_mfma_f32_16x16x32_bf16(     \
              af_[rt_], bv_, acc[rt_][ct_], 0, 0, 0);                  \
      }                                                                \
    }                                                                  \
  } while (0)

  uint4 bc[2][4], bn[2][4];
  // prologue: D0 -> raw0, D1 -> raw1, B0 -> regs; drain D0 (keep 10); cvt own rows
  STAGE(0, 0);
  STAGE(1, 1);
  LOADB(bc, 0);
  asm volatile("s_waitcnt vmcnt(10)" ::: "memory");
  CVT(0, 0);                            // own-wave rows: no barrier needed

  int rb_cvt = 1, rb_stage = 2;         // (kt+1)%3, (kt+2)%3
  for (int kt = 0; kt < 32; ++kt) {
    if (kt < 31) LOADB(bn, kt + 1);
    // steady outstanding/wave: D(kt+1)=2 then B(kt+1)=8 -> drain D, keep B
    if (kt < 31) {
      asm volatile("s_waitcnt vmcnt(8) lgkmcnt(0)" ::: "memory");
    } else {
      asm volatile("s_waitcnt vmcnt(0) lgkmcnt(0)" ::: "memory");
    }
    __builtin_amdgcn_s_barrier();
    asm volatile("" ::: "memory");

    if (kt < 30) STAGE(rb_stage, kt + 2);   // raw[rb_stage]: its readers done last iter
    if (kt < 31) CVT(rb_cvt, (kt + 1) & 1);
    __builtin_amdgcn_s_setprio(1);
    MFMA_STEP(kt & 1);
    __builtin_amdgcn_s_setprio(0);
    if (kt < 31) {
      #pragma unroll
      for (int s_ = 0; s_ < 2; ++s_)
        #pragma unroll
        for (int ct_ = 0; ct_ < 4; ++ct_)
          bc[s_][ct_] = bn[s_][ct_];
    }
    rb_cvt = (rb_cvt == 2) ? 0 : rb_cvt + 1;
    rb_stage = (rb_stage == 2) ? 0 : rb_stage + 1;
  }

#undef STAGE
#undef LOADB
#undef CVT
#undef MFMA_STEP

  // ---- epilogue: tanh + W3 dot in registers ----
  // acc[rt][ct][j] = c[row = rt*16 + g*4 + j][col = wid*64 + ct*16 + l15]
  float pp[4], w3v[4];
  #pragma unroll
  for (int ct = 0; ct < 4; ++ct) {
    int col = wid * 64 + ct * 16 + l15;
    pp[ct] = pprime[b * DIM_ + col];
    w3v[ct] = W3[col];
  }
  #pragma unroll
  for (int rt = 0; rt < 4; ++rt) {
    #pragma unroll
    for (int j = 0; j < 4; ++j) {
      float v = fast_tanh(acc[rt][0][j] + pp[0]) * w3v[0]
              + fast_tanh(acc[rt][1][j] + pp[1]) * w3v[1]
              + fast_tanh(acc[rt][2][j] + pp[2]) * w3v[2]
              + fast_tanh(acc[rt][3][j] + pp[3]) * w3v[3];
      v += __shfl_xor(v, 1);
      v += __shfl_xor(v, 2);
      v += __shfl_xor(v, 4);
      v += __shfl_xor(v, 8);
      if (l15 == 0) lds_part[wid][rt * 16 + g * 4 + j] = v;
    }
  }
  __syncthreads();

  // ---- softmax over R=64 (wave 0) ----
  if (t < R_) {
    float s = 0.f;
    #pragma unroll
    for (int w = 0; w < 8; ++w) s += lds_part[w][t];
    float m = s;
    #pragma unroll
    for (int off = 32; off >= 1; off >>= 1) m = fmaxf(m, __shfl_xor(m, off));
    float e = __expf(s - m);
    float su = e;
    #pragma unroll
    for (int off = 32; off >= 1; off >>= 1) su += __shfl_xor(su, off);
    lds_aw[t] = e / su;
  }
  __syncthreads();

  // ---- weighted sum: q[b][f] = sum_r aw[r]*feat[b][r][f]; feat[b] is L2-hot ----
  {
    int f0 = t * 4;                     // 512 thr x 4 cols = 2048
    float4 qa = (float4){0.f, 0.f, 0.f, 0.f};
    const float* fp = featB + f0;
    #pragma unroll 8
    for (int r = 0; r < R_; ++r) {
      float a = lds_aw[r];
      float4 v = *reinterpret_cast<const float4*>(fp + (size_t)r * F_);
      qa.x += a * v.x; qa.y += a * v.y; qa.z += a * v.z; qa.w += a * v.w;
    }
    *reinterpret_cast<float4*>(out + (size_t)b * F_ + f0) = qa;
  }
}

extern "C" void kernel_launch(void* const* d_in, const int* in_sizes, int n_in,
                              void* d_out, int out_size, void* d_ws, size_t ws_size,
                              hipStream_t stream) {
  const float* feat = (const float*)d_in[0];   // [B,R,F]
  const float* prev = (const float*)d_in[1];   // [B,H]
  const float* Ww   = (const float*)d_in[2];   // [F,DIM]
  const float* Wb   = (const float*)d_in[3];   // [DIM]
  const float* W2w  = (const float*)d_in[4];   // [H,DIM]
  const float* W2b  = (const float*)d_in[5];   // [DIM]
  const float* W3w  = (const float*)d_in[6];   // [DIM,1]
  // d_in[7] = W3_b: cancels in softmax
  float* out = (float*)d_out;

  ushort* wpack  = (ushort*)d_ws;                                   // 2 MB
  float*  pprime = (float*)((char*)d_ws + (size_t)F_ * DIM_ * 2);   // 512 KB

  pack_w_k<<<(F_ * DIM_) / 256, 256, 0, stream>>>(Ww, wpack);
  prep_p_k<<<256, 256, 0, stream>>>(prev, W2w, W2b, Wb, pprime);
  fused_k<<<B_, 512, 0, stream>>>(feat, wpack, pprime, W3w, out);
}

// Round 10
// 98.371 us; speedup vs baseline: 1.1504x; 1.0527x over previous
//
#include <hip/hip_runtime.h>
#include <hip/hip_bf16.h>

// attention_84464826843938: additive-attention pooling, MI355X (gfx950)
//
// R10: R7 dataflow (best measured: 2 blocks/CU) + K-loop unroll x2 with
// alternating B register sets (bA/bB) -> B(kt+1) is loaded one full
// barrier-delimited half-iteration before its MFMA, no end-of-iter reg copies
// (R7/R9 flaw: bn->bc copy forced same-iteration drain of B loads).
// vmcnt per half e: queue [S(e+1)2, b(e)4, S(e+2)2, b(e+1)4]=12 -> steady
// vmcnt(10) drains S(e+1) for CVT; e=30 -> vmcnt(8); e=31 -> vmcnt(0).
// Setup kernels merged into one launch.

#define B_ 256
#define R_ 64
#define F_ 2048
#define H_ 512
#define DIM_ 512

typedef short bf16x8 __attribute__((ext_vector_type(8)));
typedef float f32x4 __attribute__((ext_vector_type(4)));

__device__ __forceinline__ ushort f2bf(float x) {
  __hip_bfloat16 h = __float2bfloat16(x);
  return __builtin_bit_cast(ushort, h);
}

__device__ __forceinline__ uint4 pack8(float4 x, float4 y) {
  uint4 r;
  r.x = (uint)f2bf(x.x) | ((uint)f2bf(x.y) << 16);
  r.y = (uint)f2bf(x.z) | ((uint)f2bf(x.w) << 16);
  r.z = (uint)f2bf(y.x) | ((uint)f2bf(y.y) << 16);
  r.w = (uint)f2bf(y.z) | ((uint)f2bf(y.w) << 16);
  return r;
}

__device__ __forceinline__ void gld16(const float* g, float* l) {
  __builtin_amdgcn_global_load_lds(
      (const __attribute__((address_space(1))) unsigned int*)(g),
      (__attribute__((address_space(3))) unsigned int*)(l),
      16, 0, 0);
}

// blocks [0,4096): wpack[((kt*32+ctg)*64 + g*16 + c)*8 + i] = bf16(W_w[kt*32+g*8+i][ctg*16+c])
// blocks [4096,4352): p'[b][d] = prev[b]@W2_w[:,d] + W2_b[d] + W_b[d]
__global__ __launch_bounds__(256) void setup_k(const float* __restrict__ Ww,
                                               ushort* __restrict__ wpack,
                                               const float* __restrict__ prev,
                                               const float* __restrict__ W2w,
                                               const float* __restrict__ W2b,
                                               const float* __restrict__ Wb,
                                               float* __restrict__ pprime) {
  __shared__ float lprev[8][H_];
  if (blockIdx.x < 4096) {
    int idx = blockIdx.x * 256 + threadIdx.x;
    float v = Ww[idx];
    int k = idx >> 9;
    int d = idx & 511;
    int kt = k >> 5, kr = k & 31;
    int g = kr >> 3, i = kr & 7;
    int ctg = d >> 4, c = d & 15;
    size_t dst = ((size_t)((kt * 32 + ctg) * 64 + g * 16 + c)) * 8 + (size_t)i;
    wpack[dst] = f2bf(v);
    return;
  }
  int pb = blockIdx.x - 4096;
  int bg = pb >> 3;
  int d0 = (pb & 7) * 64;
  int t = threadIdx.x;
  const float4* src = reinterpret_cast<const float4*>(prev + (size_t)bg * 8 * H_);
  float4* dst = reinterpret_cast<float4*>(&lprev[0][0]);
  for (int i = t; i < 8 * H_ / 4; i += 256) dst[i] = src[i];
  __syncthreads();
  int d = d0 + (t & 63);
  int bq = t >> 6;
  float a0 = 0.f, a1 = 0.f;
  #pragma unroll 8
  for (int h = 0; h < H_; ++h) {
    float wv = W2w[h * DIM_ + d];
    a0 += lprev[bq][h] * wv;
    a1 += lprev[bq + 4][h] * wv;
  }
  float bias = W2b[d] + Wb[d];
  pprime[(size_t)(bg * 8 + bq) * DIM_ + d] = a0 + bias;
  pprime[(size_t)(bg * 8 + bq + 4) * DIM_ + d] = a1 + bias;
}

__device__ __forceinline__ float fast_tanh(float x) {
  float e = __expf(2.f * x);
  return 1.f - 2.f / (e + 1.f);
}

// sp[b*2+slice][r] = sum_{d in slice's 256 cols} tanh(c[b][r][d]+p'[b][d])*W3[d]
__global__ __launch_bounds__(512, 4) void score_k(const float* __restrict__ feat,
                                                  const ushort* __restrict__ wpack,
                                                  const float* __restrict__ pprime,
                                                  const float* __restrict__ W3,
                                                  float* __restrict__ sp) {
  int slice = blockIdx.x >> 8;          // slice-major: both slices of b same XCD
  int b = blockIdx.x & 255;
  int t = threadIdx.x;
  int wid = t >> 6;                     // 8 waves; wave owns cols [wid*32,+32)
  int l = t & 63;
  int l15 = l & 15, g = l >> 4;
  const float* featB = feat + (size_t)b * R_ * F_;

  // raw[buf][row][c16]: holds global 16B-chunk (c16 ^ (row&15))  [src-swizzle]
  __shared__ float raw[3][4096];        // 3 x 16 KB DMA ring
  // frg[buf][kc*64 + (row ^ ((kc*2)&15))] = bf16 A[row][k=kc*8..+8]
  __shared__ uint4 frg[2][512];         // 2 x 8 KB
  __shared__ float lds_part[8][R_];

  f32x4 acc[4][2];
  #pragma unroll
  for (int rt = 0; rt < 4; ++rt)
    #pragma unroll
    for (int ct = 0; ct < 2; ++ct)
      acc[rt][ct] = (f32x4){0.f, 0.f, 0.f, 0.f};

  // ---- DMA geometry: wave wid covers rows [wid*4, wid*4+4) and +32
  int srow = wid * 4 + g;
  int sch = l15 ^ (srow & 15);
  const float* sg0 = featB + (size_t)srow * F_ + sch * 4;
  const float* sg1 = featB + (size_t)(srow + 32) * F_ + sch * 4;

  // ---- cvt geometry: thread t -> row t>>3, k-chunk pair cj2 = (t&7)*2
  int crow = t >> 3, cj2 = (t & 7) * 2;
  int rm = crow & 15;
  int cw = (t & 7) * 64 + (crow ^ cj2);          // frag store index (cj2<=14)

  // ---- B pointer: frag(kt,s,ct) at wp + kt*32768 + s*16384 + ct*512 (ushorts)
  const ushort* wp = wpack + (size_t)(slice * 16 + wid * 2) * 512 + (size_t)l * 8;

#define STAGE(buf, kt) do {                                        \
    gld16(sg0 + (size_t)(kt) * 64, &raw[buf][wid * 256]);          \
    gld16(sg1 + (size_t)(kt) * 64, &raw[buf][2048 + wid * 256]);   \
  } while (0)

#define LOADB(dst, kt) do {                                        \
    const ushort* wpk_ = wp + (size_t)(kt) * 32768;                \
    dst[0][0] = *reinterpret_cast<const uint4*>(wpk_);             \
    dst[0][1] = *reinterpret_cast<const uint4*>(wpk_ + 512);       \
    dst[1][0] = *reinterpret_cast<const uint4*>(wpk_ + 16384);     \
    dst[1][1] = *reinterpret_cast<const uint4*>(wpk_ + 16384 + 512); \
  } while (0)

#define CVT(nb, fb) do {                                           \
    const float* rb_ = &raw[nb][crow * 64];                        \
    float4 x_ = *reinterpret_cast<const float4*>(rb_ + ((cj2 + 0) ^ rm) * 4); \
    float4 y_ = *reinterpret_cast<const float4*>(rb_ + ((cj2 + 1) ^ rm) * 4); \
    frg[fb][cw] = pack8(x_, y_);                                   \
  } while (0)

#define MFMA_STEP(fb, BSET) do {                                   \
    _Pragma("unroll")                                              \
    for (int s_ = 0; s_ < 2; ++s_) {                               \
      bf16x8 af_[4];                                               \
      int kc_ = s_ * 4 + g;                                        \
      _Pragma("unroll")                                            \
      for (int rt_ = 0; rt_ < 4; ++rt_)                            \
        af_[rt_] = __builtin_bit_cast(bf16x8,                      \
            frg[fb][kc_ * 64 + ((rt_ * 16 + l15) ^ ((kc_ * 2) & 15))]); \
      _Pragma("unroll")                                            \
      for (int ct_ = 0; ct_ < 2; ++ct_) {                          \
        bf16x8 bv_ = __builtin_bit_cast(bf16x8, BSET[s_][ct_]);    \
        _Pragma("unroll")                                          \
        for (int rt_ = 0; rt_ < 4; ++rt_)                          \
          acc[rt_][ct_] = __builtin_amdgcn_mfma_f32_16x16x32_bf16( \
              af_[rt_], bv_, acc[rt_][ct_], 0, 0, 0);              \
      }                                                            \
    }                                                              \
  } while (0)

#define BARRIER_VM(N) do {                                         \
    asm volatile("s_waitcnt vmcnt(" #N ") lgkmcnt(0)" ::: "memory"); \
    __builtin_amdgcn_s_barrier();                                  \
    asm volatile("" ::: "memory");                                 \
  } while (0)

  uint4 bA[2][2], bB[2][2];
  // prologue: D0, D1 in flight; bA=B(0). Drain D0 (keep D1+bA=6), publish raw0.
  STAGE(0, 0);
  STAGE(1, 1);
  LOADB(bA, 0);
  asm volatile("s_waitcnt vmcnt(6)" ::: "memory");
  __builtin_amdgcn_s_barrier();
  asm volatile("" ::: "memory");
  STAGE(2, 2);
  CVT(0, 0);                            // tile 0 -> frg[0]

  // main loop: halves e=0..27 (14 iterations of 2); ring: stage (e+3)%3, cvt (e+1)%3
  int st_b = 0, cv_b = 1;
  for (int e = 0; e < 28; e += 2) {
    // half A: compute tile e (frg[0], bA); cvt e+1 -> frg[1]; stage e+3; load B(e+1)
    LOADB(bB, e + 1);
    BARRIER_VM(10);
    STAGE(st_b, e + 3);
    CVT(cv_b, 1);
    __builtin_amdgcn_s_setprio(1);
    MFMA_STEP(0, bA);
    __builtin_amdgcn_s_setprio(0);
    st_b = (st_b == 2) ? 0 : st_b + 1;
    cv_b = (cv_b == 2) ? 0 : cv_b + 1;
    // half B: compute tile e+1 (frg[1], bB); cvt e+2 -> frg[0]; stage e+4; load B(e+2)
    LOADB(bA, e + 2);
    BARRIER_VM(10);
    STAGE(st_b, e + 4);
    CVT(cv_b, 0);
    __builtin_amdgcn_s_setprio(1);
    MFMA_STEP(1, bB);
    __builtin_amdgcn_s_setprio(0);
    st_b = (st_b == 2) ? 0 : st_b + 1;
    cv_b = (cv_b == 2) ? 0 : cv_b + 1;
  }
  // peel e=28..31  (rings: cvt(e+1)%3 = 2,0,1; stage 31 -> buf 31%3=2... e=28:(31)%3=1)
  // e=28: compute frg[0] w/ bA; cvt 29 -> frg[1] (buf 29%3=2); stage 31 (buf 1)
  LOADB(bB, 29);
  BARRIER_VM(10);
  STAGE(1, 31);
  CVT(2, 1);
  __builtin_amdgcn_s_setprio(1);
  MFMA_STEP(0, bA);
  __builtin_amdgcn_s_setprio(0);
  // e=29: compute frg[1] w/ bB; cvt 30 -> frg[0] (buf 30%3=0); no stage
  LOADB(bA, 30);
  BARRIER_VM(10);
  CVT(0, 0);
  __builtin_amdgcn_s_setprio(1);
  MFMA_STEP(1, bB);
  __builtin_amdgcn_s_setprio(0);
  // e=30: compute frg[0] w/ bA; cvt 31 -> frg[1] (buf 31%3=1); need S31 -> vm(8)
  LOADB(bB, 31);
  BARRIER_VM(8);
  CVT(1, 1);
  __builtin_amdgcn_s_setprio(1);
  MFMA_STEP(0, bA);
  __builtin_amdgcn_s_setprio(0);
  // e=31: compute frg[1] w/ bB
  BARRIER_VM(0);
  __builtin_amdgcn_s_setprio(1);
  MFMA_STEP(1, bB);
  __builtin_amdgcn_s_setprio(0);

#undef STAGE
#undef LOADB
#undef CVT
#undef MFMA_STEP
#undef BARRIER_VM

  // epilogue: tanh + W3 dot in registers
  // acc[rt][ct][j] = c[row = rt*16 + g*4 + j][col = slice*256 + wid*32 + ct*16 + l15]
  float pp[2], w3v[2];
  #pragma unroll
  for (int ct = 0; ct < 2; ++ct) {
    int col = slice * 256 + wid * 32 + ct * 16 + l15;
    pp[ct] = pprime[b * DIM_ + col];
    w3v[ct] = W3[col];
  }
  #pragma unroll
  for (int rt = 0; rt < 4; ++rt) {
    #pragma unroll
    for (int j = 0; j < 4; ++j) {
      float v = fast_tanh(acc[rt][0][j] + pp[0]) * w3v[0]
              + fast_tanh(acc[rt][1][j] + pp[1]) * w3v[1];
      v += __shfl_xor(v, 1);
      v += __shfl_xor(v, 2);
      v += __shfl_xor(v, 4);
      v += __shfl_xor(v, 8);
      if (l15 == 0) lds_part[wid][rt * 16 + g * 4 + j] = v;
    }
  }
  __syncthreads();

  if (t < R_) {
    float s = 0.f;
    #pragma unroll
    for (int w = 0; w < 8; ++w) s += lds_part[w][t];
    sp[((size_t)b * 2 + slice) * R_ + t] = s;
  }
}

// softmax + weighted sum: grid = B*4, 256 thr, 512 f per block
__global__ __launch_bounds__(256) void wsum_k(const float* __restrict__ feat,
                                              const float* __restrict__ sp,
                                              float* __restrict__ out) {
  int b = blockIdx.x >> 2;
  int f0 = (blockIdx.x & 3) * 512;
  int t = threadIdx.x;
  __shared__ float lds_aw[R_];

  if (t < R_) {
    float s = sp[((size_t)b * 2 + 0) * R_ + t] + sp[((size_t)b * 2 + 1) * R_ + t];
    float m = s;
    #pragma unroll
    for (int off = 32; off >= 1; off >>= 1) m = fmaxf(m, __shfl_xor(m, off));
    float e = __expf(s - m);
    float su = e;
    #pragma unroll
    for (int off = 32; off >= 1; off >>= 1) su += __shfl_xor(su, off);
    lds_aw[t] = e / su;
  }
  __syncthreads();

  const float* fp = feat + (size_t)b * R_ * F_ + f0 + t * 2;
  float qx = 0.f, qy = 0.f;
  #pragma unroll 8
  for (int r = 0; r < R_; ++r) {
    float a = lds_aw[r];
    float2 v = *reinterpret_cast<const float2*>(fp + (size_t)r * F_);
    qx += a * v.x;
    qy += a * v.y;
  }
  *reinterpret_cast<float2*>(out + (size_t)b * F_ + f0 + t * 2) = (float2){qx, qy};
}

extern "C" void kernel_launch(void* const* d_in, const int* in_sizes, int n_in,
                              void* d_out, int out_size, void* d_ws, size_t ws_size,
                              hipStream_t stream) {
  const float* feat = (const float*)d_in[0];   // [B,R,F]
  const float* prev = (const float*)d_in[1];   // [B,H]
  const float* Ww   = (const float*)d_in[2];   // [F,DIM]
  const float* Wb   = (const float*)d_in[3];   // [DIM]
  const float* W2w  = (const float*)d_in[4];   // [H,DIM]
  const float* W2b  = (const float*)d_in[5];   // [DIM]
  const float* W3w  = (const float*)d_in[6];   // [DIM,1]
  // d_in[7] = W3_b: cancels in softmax
  float* out = (float*)d_out;

  ushort* wpack  = (ushort*)d_ws;                                          // 2 MB
  float*  pprime = (float*)((char*)d_ws + (size_t)F_ * DIM_ * 2);          // 512 KB
  float*  sp     = (float*)((char*)d_ws + (size_t)F_ * DIM_ * 2
                                        + (size_t)B_ * DIM_ * 4);          // 128 KB

  setup_k<<<4096 + 256, 256, 0, stream>>>(Ww, wpack, prev, W2w, W2b, Wb, pprime);
  score_k<<<B_ * 2, 512, 0, stream>>>(feat, wpack, pprime, W3w, sp);
  wsum_k<<<B_ * 4, 256, 0, stream>>>(feat, sp, out);
}